// Round 1
// baseline (179.017 us; speedup 1.0000x reference)
//
#include <hip/hip_runtime.h>
#include <math.h>

// Problem constants (SpatialSelectiveMRF): s=60000 rows, K=200 components,
// dz=64 selective dims, 3 spatial dims, n=6 neighbors. f32 in/out.
#define DZ 64
#define KK 200
#define KP 204          // LDS leading-dim pad: multiple of 4 (16B rows for b128), 204%8==4 keeps staging writes spread
#define NS 3
#define NNB 6
#define ROWS_PER_WAVE 8
#define ROWS_PER_BLOCK 32   // 4 waves * 8 rows

__device__ __forceinline__ float readlane_f(float v, int lane) {
    // v_readlane_b32 -> SGPR broadcast; stays off the LDS pipe (unlike __shfl's ds_bpermute)
    return __int_as_float(__builtin_amdgcn_readlane(__float_as_int(v), lane));
}

__device__ __forceinline__ float wave_max(float v) {
#pragma unroll
    for (int off = 32; off > 0; off >>= 1) v = fmaxf(v, __shfl_xor(v, off));
    return v;
}
__device__ __forceinline__ float wave_sum(float v) {
#pragma unroll
    for (int off = 32; off > 0; off >>= 1) v += __shfl_xor(v, off);
    return v;
}

// Kernel 1: per-row softmax over K, writes clipped Q row (Qc) + expected point energy.
// U_k = 0.5*(zz+ss) + 0.5*67*log(2pi) - Lhat_k,  Lhat_k = z.mu_k + s.smu_k - 0.5*(|mu_k|^2+|smu_k|^2)
// softmax(-U) == softmax(Lhat) (per-row constants drop out of softmax).
__global__ __launch_bounds__(256, 2) void
k_point(const float* __restrict__ Z, const float* __restrict__ S,
        const float* __restrict__ selmu, const float* __restrict__ spamu,
        float* __restrict__ Qc, float* __restrict__ pointbuf,
        int sRows, int nGroups)
{
    __shared__ float muT[DZ * KP];    // 52224 B, transposed [d][k]
    __shared__ float spaT[NS * KP];   //  2448 B
    __shared__ float normc[KP];       //   816 B   total ~55.5 KB -> 2 blocks/CU

    const int tid = threadIdx.x;

    // Stage selmu transposed. Lanes take consecutive k -> LDS writes conflict-free;
    // global float4 reads are strided (L2-resident, 51KB total, acceptable).
    for (int idx = tid; idx < 16 * KK; idx += 256) {
        int dg = idx / KK;            // 0..15 (group of 4 d)
        int k  = idx - dg * KK;       // 0..199
        float4 v = ((const float4*)selmu)[k * 16 + dg];
        muT[(4 * dg + 0) * KP + k] = v.x;
        muT[(4 * dg + 1) * KP + k] = v.y;
        muT[(4 * dg + 2) * KP + k] = v.z;
        muT[(4 * dg + 3) * KP + k] = v.w;
    }
    for (int idx = tid; idx < NS * KK; idx += 256) {
        int c = idx / KK;
        int k = idx - c * KK;
        spaT[c * KP + k] = spamu[k * NS + c];
    }
    __syncthreads();
    for (int k = tid; k < KK; k += 256) {
        float acc = 0.f;
#pragma unroll 16
        for (int d = 0; d < DZ; ++d) { float m = muT[d * KP + k]; acc += m * m; }
#pragma unroll
        for (int c = 0; c < NS; ++c) { float m = spaT[c * KP + k]; acc += m * m; }
        normc[k] = 0.5f * acc;
    }
    __syncthreads();

    const int wave = tid >> 6;
    const int lane = tid & 63;
    const bool kActive = (lane < KK / 4);          // 50 lanes carry 4 consecutive k each
    const int k0  = 4 * lane;
    const int k0c = kActive ? k0 : (KK - 4);       // idle lanes read a safe address

    const float cLog = 0.5f * (float)(DZ + NS) * 1.8378770664093453f; // log(2*pi)

    for (int g = blockIdx.x; g < nGroups; g += gridDim.x) {
        const int rowBase = g * ROWS_PER_BLOCK + wave * ROWS_PER_WAVE;

        float zreg[ROWS_PER_WAVE];
#pragma unroll
        for (int r = 0; r < ROWS_PER_WAVE; ++r) {
            int row = rowBase + r;
            zreg[r] = (row < sRows) ? Z[(size_t)row * DZ + lane] : 0.f;
        }
        float sreg = 0.f;
        if (lane < ROWS_PER_WAVE * NS && (rowBase + lane / NS) < sRows)
            sreg = S[(size_t)rowBase * NS + lane];

        // init accumulators with spatial dot - normc; idle lanes pinned at -1e30
        float acc[ROWS_PER_WAVE][4];
        const float4 n4  = *(const float4*)&normc[k0c];
        const float4 sp0 = *(const float4*)&spaT[0 * KP + k0c];
        const float4 sp1 = *(const float4*)&spaT[1 * KP + k0c];
        const float4 sp2 = *(const float4*)&spaT[2 * KP + k0c];
#pragma unroll
        for (int r = 0; r < ROWS_PER_WAVE; ++r) {
            float a0 = readlane_f(sreg, r * NS + 0);
            float a1 = readlane_f(sreg, r * NS + 1);
            float a2 = readlane_f(sreg, r * NS + 2);
            float v0 = a0 * sp0.x + a1 * sp1.x + a2 * sp2.x - n4.x;
            float v1 = a0 * sp0.y + a1 * sp1.y + a2 * sp2.y - n4.y;
            float v2 = a0 * sp0.z + a1 * sp1.z + a2 * sp2.z - n4.z;
            float v3 = a0 * sp0.w + a1 * sp1.w + a2 * sp2.w - n4.w;
            acc[r][0] = kActive ? v0 : -1e30f;
            acc[r][1] = kActive ? v1 : -1e30f;
            acc[r][2] = kActive ? v2 : -1e30f;
            acc[r][3] = kActive ? v3 : -1e30f;
        }

        // main dot: 1 ds_read_b128 feeds 8 rows x 4 k = 32 FMAs
#pragma unroll 4
        for (int d = 0; d < DZ; ++d) {
            const float4 m4 = *(const float4*)&muT[d * KP + k0c];
#pragma unroll
            for (int r = 0; r < ROWS_PER_WAVE; ++r) {
                const float zb = readlane_f(zreg[r], d);
                acc[r][0] = fmaf(zb, m4.x, acc[r][0]);
                acc[r][1] = fmaf(zb, m4.y, acc[r][1]);
                acc[r][2] = fmaf(zb, m4.z, acc[r][2]);
                acc[r][3] = fmaf(zb, m4.w, acc[r][3]);
            }
        }

#pragma unroll
        for (int r = 0; r < ROWS_PER_WAVE; ++r) {
            const int row = rowBase + r;
            float zz = wave_sum(zreg[r] * zreg[r]);
            float b0 = readlane_f(sreg, r * NS + 0);
            float b1 = readlane_f(sreg, r * NS + 1);
            float b2 = readlane_f(sreg, r * NS + 2);
            float ss = b0 * b0 + b1 * b1 + b2 * b2;

            float m = fmaxf(fmaxf(acc[r][0], acc[r][1]), fmaxf(acc[r][2], acc[r][3]));
            m = wave_max(m);
            float e0 = __expf(acc[r][0] - m);   // idle lanes: exp(-1e30-m) == 0
            float e1 = __expf(acc[r][1] - m);
            float e2 = __expf(acc[r][2] - m);
            float e3 = __expf(acc[r][3] - m);
            float sl = e0 + e1 + e2 + e3;
            float pl = e0 * acc[r][0] + e1 * acc[r][1] + e2 * acc[r][2] + e3 * acc[r][3];
#pragma unroll
            for (int off = 32; off > 0; off >>= 1) {
                sl += __shfl_xor(sl, off);
                pl += __shfl_xor(pl, off);
            }
            float invS = 1.0f / sl;
            if (row < sRows) {
                if (lane == 0)
                    pointbuf[row] = 0.5f * (zz + ss) + cLog - pl * invS;
                if (kActive) {
                    float4 q;
                    q.x = fminf(fmaxf(e0 * invS, 1e-6f), 1.0f - 1e-6f);
                    q.y = fminf(fmaxf(e1 * invS, 1e-6f), 1.0f - 1e-6f);
                    q.z = fminf(fmaxf(e2 * invS, 1e-6f), 1.0f - 1e-6f);
                    q.w = fminf(fmaxf(e3 * invS, 1e-6f), 1.0f - 1e-6f);
                    *(float4*)(Qc + (size_t)row * KK + k0) = q;
                }
            }
        }
    }
}

// Kernel 2: doublet energy. Wave per row: dot own Qc row with 6 gathered rows.
__global__ __launch_bounds__(256) void
k_doublet(const float* __restrict__ Qc, const float* __restrict__ pointbuf,
          const int* __restrict__ D, float* __restrict__ out, int sRows)
{
    const int lane = threadIdx.x & 63;
    const int wave = threadIdx.x >> 6;
    const int row = blockIdx.x * 4 + wave;
    if (row >= sRows) return;
    const bool l50 = (lane < KK / 4);

    float4 own = make_float4(0.f, 0.f, 0.f, 0.f);
    if (l50) own = ((const float4*)(Qc + (size_t)row * KK))[lane];

    float doublet = 0.f;
#pragma unroll
    for (int j = 0; j < NNB; ++j) {
        int dj = D[(size_t)row * NNB + j];
        float p = 0.f;
        if (dj >= 0 && l50) {
            float4 nb = ((const float4*)(Qc + (size_t)dj * KK))[lane];
            p = own.x * nb.x + own.y * nb.y + own.z * nb.z + own.w * nb.w;
        }
        p = wave_sum(p);
        if (dj >= 0) doublet -= __logf(p);
    }
    if (lane == 0) out[row] = pointbuf[row] + doublet;
}

extern "C" void kernel_launch(void* const* d_in, const int* in_sizes, int n_in,
                              void* d_out, int out_size, void* d_ws, size_t ws_size,
                              hipStream_t stream) {
    const float* Z     = (const float*)d_in[0];
    const float* S     = (const float*)d_in[1];
    const int*   D     = (const int*)d_in[2];
    const float* selmu = (const float*)d_in[3];
    const float* spamu = (const float*)d_in[4];
    float* out = (float*)d_out;
    const int s = out_size;                    // 60000

    float* Qc       = (float*)d_ws;            // s*KK floats = 48 MB
    float* pointbuf = Qc + (size_t)s * KK;     // s floats

    const int nGroups = (s + ROWS_PER_BLOCK - 1) / ROWS_PER_BLOCK;   // 1875
    const int grid1 = nGroups < 512 ? nGroups : 512;                 // 2 blocks/CU resident
    k_point<<<grid1, 256, 0, stream>>>(Z, S, selmu, spamu, Qc, pointbuf, s, nGroups);

    const int grid2 = (s + 3) / 4;             // wave per row, 4 rows/block
    k_doublet<<<grid2, 256, 0, stream>>>(Qc, pointbuf, D, out, s);
}

// Round 2
// 162.491 us; speedup vs baseline: 1.1017x; 1.1017x over previous
//
#include <hip/hip_runtime.h>
#include <math.h>

// SpatialSelectiveMRF: s=60000 rows, K=200 components, dz=64, 3 spatial, n=6 neighbors.
#define DZ 64
#define KK 200
#define KP 200          // LDS leading dim: 200 floats = 800B rows; lanes read consecutive float4 -> conflict-free
#define NS 3
#define NNB 6
#define RPW 8           // rows per wave
#define RPB 32          // rows per block (4 waves)

typedef unsigned int uint32;

__device__ __forceinline__ float readlane_f(float v, int lane) {
    return __int_as_float(__builtin_amdgcn_readlane(__float_as_int(v), lane));
}
__device__ __forceinline__ float wave_max(float v) {
#pragma unroll
    for (int off = 32; off > 0; off >>= 1) v = fmaxf(v, __shfl_xor(v, off));
    return v;
}
__device__ __forceinline__ float wave_sum(float v) {
#pragma unroll
    for (int off = 32; off > 0; off >>= 1) v += __shfl_xor(v, off);
    return v;
}
// f32 -> bf16 round-to-nearest-even (inputs are positive normals in [1e-6, 1])
__device__ __forceinline__ uint32 f2bf(float f) {
    uint32 u = __float_as_uint(f);
    return (u + 0x7fffu + ((u >> 16) & 1u)) >> 16;
}

// Kernel 1: per-row softmax over K -> bf16 Qc row + expected point energy.
// softmax(-U) == softmax(Lhat), Lhat_k = z.mu_k + s.smu_k - 0.5*(|mu_k|^2+|smu_k|^2)
__global__ __launch_bounds__(256, 3) void
k_point(const float* __restrict__ Z, const float* __restrict__ S,
        const float* __restrict__ selmu, const float* __restrict__ spamu,
        unsigned short* __restrict__ Qc, float* __restrict__ pointbuf,
        int* __restrict__ cnt, int sRows, int nGroups)
{
    __shared__ float muT[DZ * KP];   // 51200 B -> exactly 3 blocks/CU (153.6 of 160 KB)
    __shared__ int sg[2];

    const int tid = threadIdx.x;
    if (tid == 0) sg[0] = atomicAdd(cnt, 1);   // first group fetch, overlaps staging

    // Stage selmu transposed [d][k]; lanes take consecutive k -> conflict-free LDS writes.
    for (int idx = tid; idx < 16 * KK; idx += 256) {
        int dg = idx / KK;
        int k  = idx - dg * KK;
        float4 v = ((const float4*)selmu)[k * 16 + dg];
        muT[(4 * dg + 0) * KP + k] = v.x;
        muT[(4 * dg + 1) * KP + k] = v.y;
        muT[(4 * dg + 2) * KP + k] = v.z;
        muT[(4 * dg + 3) * KP + k] = v.w;
    }
    __syncthreads();   // covers muT staging AND sg[0]

    const int wave = tid >> 6;
    const int lane = tid & 63;
    const bool kActive = (lane < KK / 4);      // 50 lanes x 4 consecutive k
    const int k0  = 4 * lane;
    const int k0c = kActive ? k0 : (KK - 4);

    // Per-lane constants (once per kernel): spatial mu (contiguous 12 floats) + norm consts.
    float4 sp0, sp1, sp2, n4;
    {
        const float4* sp4 = (const float4*)(spamu + k0c * NS);  // 48B-aligned
        float4 f0 = sp4[0], f1 = sp4[1], f2 = sp4[2];
        sp0 = make_float4(f0.x, f0.w, f1.z, f2.y);  // component 0 of k0..k3
        sp1 = make_float4(f0.y, f1.x, f1.w, f2.z);
        sp2 = make_float4(f0.z, f1.y, f2.x, f2.w);
        float n0 = sp0.x*sp0.x + sp1.x*sp1.x + sp2.x*sp2.x;
        float n1 = sp0.y*sp0.y + sp1.y*sp1.y + sp2.y*sp2.y;
        float n2 = sp0.z*sp0.z + sp1.z*sp1.z + sp2.z*sp2.z;
        float n3 = sp0.w*sp0.w + sp1.w*sp1.w + sp2.w*sp2.w;
#pragma unroll 8
        for (int d = 0; d < DZ; ++d) {
            float4 m = *(const float4*)&muT[d * KP + k0c];
            n0 += m.x*m.x; n1 += m.y*m.y; n2 += m.z*m.z; n3 += m.w*m.w;
        }
        n4 = make_float4(0.5f*n0, 0.5f*n1, 0.5f*n2, 0.5f*n3);
    }

    const float cLog = 0.5f * (float)(DZ + NS) * 1.8378770664093453f; // 0.5*(d)*log(2pi)

    int slot = 0;
    int g = sg[0];
    while (g < nGroups) {
        if (tid == 0) sg[slot ^ 1] = atomicAdd(cnt, 1);   // prefetch next group id

        const int rowBase = g * RPB + wave * RPW;

        float zreg[RPW];
#pragma unroll
        for (int r = 0; r < RPW; ++r) {
            int row = rowBase + r;
            zreg[r] = (row < sRows) ? Z[(size_t)row * DZ + lane] : 0.f;
        }
        float sreg = 0.f;
        if (lane < RPW * NS && (rowBase + lane / NS) < sRows)
            sreg = S[(size_t)rowBase * NS + lane];

        float acc[RPW][4];
#pragma unroll
        for (int r = 0; r < RPW; ++r) {
            float a0 = readlane_f(sreg, r * NS + 0);
            float a1 = readlane_f(sreg, r * NS + 1);
            float a2 = readlane_f(sreg, r * NS + 2);
            float v0 = a0 * sp0.x + a1 * sp1.x + a2 * sp2.x - n4.x;
            float v1 = a0 * sp0.y + a1 * sp1.y + a2 * sp2.y - n4.y;
            float v2 = a0 * sp0.z + a1 * sp1.z + a2 * sp2.z - n4.z;
            float v3 = a0 * sp0.w + a1 * sp1.w + a2 * sp2.w - n4.w;
            acc[r][0] = kActive ? v0 : -1e30f;
            acc[r][1] = kActive ? v1 : -1e30f;
            acc[r][2] = kActive ? v2 : -1e30f;
            acc[r][3] = kActive ? v3 : -1e30f;
        }

        // main dot: 1 ds_read_b128 feeds 8 rows x 4 k = 32 FMAs
#pragma unroll 4
        for (int d = 0; d < DZ; ++d) {
            const float4 m4 = *(const float4*)&muT[d * KP + k0c];
#pragma unroll
            for (int r = 0; r < RPW; ++r) {
                const float zb = readlane_f(zreg[r], d);
                acc[r][0] = fmaf(zb, m4.x, acc[r][0]);
                acc[r][1] = fmaf(zb, m4.y, acc[r][1]);
                acc[r][2] = fmaf(zb, m4.z, acc[r][2]);
                acc[r][3] = fmaf(zb, m4.w, acc[r][3]);
            }
        }

#pragma unroll
        for (int r = 0; r < RPW; ++r) {
            const int row = rowBase + r;
            float zz = wave_sum(zreg[r] * zreg[r]);
            float b0 = readlane_f(sreg, r * NS + 0);
            float b1 = readlane_f(sreg, r * NS + 1);
            float b2 = readlane_f(sreg, r * NS + 2);
            float ss = b0 * b0 + b1 * b1 + b2 * b2;

            float m = fmaxf(fmaxf(acc[r][0], acc[r][1]), fmaxf(acc[r][2], acc[r][3]));
            m = wave_max(m);
            float e0 = __expf(acc[r][0] - m);   // idle lanes contribute exp(-inf)=0
            float e1 = __expf(acc[r][1] - m);
            float e2 = __expf(acc[r][2] - m);
            float e3 = __expf(acc[r][3] - m);
            float sl = e0 + e1 + e2 + e3;
            float pl = e0 * acc[r][0] + e1 * acc[r][1] + e2 * acc[r][2] + e3 * acc[r][3];
#pragma unroll
            for (int off = 32; off > 0; off >>= 1) {
                sl += __shfl_xor(sl, off);
                pl += __shfl_xor(pl, off);
            }
            float invS = 1.0f / sl;
            if (row < sRows) {
                if (lane == 0)
                    pointbuf[row] = 0.5f * (zz + ss) + cLog - pl * invS;
                if (kActive) {
                    float q0 = fminf(fmaxf(e0 * invS, 1e-6f), 1.0f - 1e-6f);
                    float q1 = fminf(fmaxf(e1 * invS, 1e-6f), 1.0f - 1e-6f);
                    float q2 = fminf(fmaxf(e2 * invS, 1e-6f), 1.0f - 1e-6f);
                    float q3 = fminf(fmaxf(e3 * invS, 1e-6f), 1.0f - 1e-6f);
                    uint2 w;
                    w.x = f2bf(q0) | (f2bf(q1) << 16);
                    w.y = f2bf(q2) | (f2bf(q3) << 16);
                    *(uint2*)(Qc + (size_t)row * KK + k0) = w;
                }
            }
        }

        __syncthreads();         // makes sg[slot^1] visible; no other barrier in loop
        slot ^= 1;
        g = sg[slot];
    }
}

__device__ __forceinline__ float4 bf2f4(uint2 w) {
    float4 f;
    f.x = __uint_as_float(w.x << 16);
    f.y = __uint_as_float(w.x & 0xffff0000u);
    f.z = __uint_as_float(w.y << 16);
    f.w = __uint_as_float(w.y & 0xffff0000u);
    return f;
}

// Kernel 2: doublet energy. Wave per row: dot own bf16 Qc row with 6 gathered rows.
__global__ __launch_bounds__(256) void
k_doublet(const unsigned short* __restrict__ Qc, const float* __restrict__ pointbuf,
          const int* __restrict__ D, float* __restrict__ out, int sRows)
{
    const int lane = threadIdx.x & 63;
    const int wave = threadIdx.x >> 6;
    const int row = blockIdx.x * 4 + wave;
    if (row >= sRows) return;
    const bool l50 = (lane < KK / 4);
    const int laneC = l50 ? lane : 0;

    float4 own = bf2f4(((const uint2*)(Qc + (size_t)row * KK))[laneC]);

    int dj[NNB];
#pragma unroll
    for (int j = 0; j < NNB; ++j) dj[j] = D[(size_t)row * NNB + j];

    float p[NNB];
#pragma unroll
    for (int j = 0; j < NNB; ++j) {
        float4 nb = bf2f4(((const uint2*)(Qc + (size_t)((dj[j] >= 0) ? dj[j] : row) * KK))[laneC]);
        float t = own.x * nb.x + own.y * nb.y + own.z * nb.z + own.w * nb.w;
        p[j] = l50 ? t : 0.f;
    }
#pragma unroll
    for (int off = 32; off > 0; off >>= 1) {
#pragma unroll
        for (int j = 0; j < NNB; ++j) p[j] += __shfl_xor(p[j], off);
    }
    float doublet = 0.f;
#pragma unroll
    for (int j = 0; j < NNB; ++j)
        if (dj[j] >= 0) doublet -= __logf(p[j]);

    if (lane == 0) out[row] = pointbuf[row] + doublet;
}

extern "C" void kernel_launch(void* const* d_in, const int* in_sizes, int n_in,
                              void* d_out, int out_size, void* d_ws, size_t ws_size,
                              hipStream_t stream) {
    const float* Z     = (const float*)d_in[0];
    const float* S     = (const float*)d_in[1];
    const int*   D     = (const int*)d_in[2];
    const float* selmu = (const float*)d_in[3];
    const float* spamu = (const float*)d_in[4];
    float* out = (float*)d_out;
    const int s = out_size;                    // 60000

    unsigned short* Qc = (unsigned short*)d_ws;                 // s*KK bf16 = 24 MB
    float* pointbuf = (float*)((char*)d_ws + (size_t)s * KK * 2);
    int* cnt = (int*)((char*)pointbuf + (size_t)s * 4);

    hipMemsetAsync(cnt, 0, 4, stream);         // work-queue counter (ws is poisoned each launch)

    const int nGroups = (s + RPB - 1) / RPB;   // 1875
    const int grid1 = 768;                     // 3 blocks/CU resident, dynamic work queue balances
    k_point<<<grid1, 256, 0, stream>>>(Z, S, selmu, spamu, Qc, pointbuf, cnt, s, nGroups);

    const int grid2 = (s + 3) / 4;             // wave per row
    k_doublet<<<grid2, 256, 0, stream>>>(Qc, pointbuf, D, out, s);
}

// Round 3
// 111.715 us; speedup vs baseline: 1.6024x; 1.4545x over previous
//
#include <hip/hip_runtime.h>
#include <math.h>

// SpatialSelectiveMRF: s=60000 rows, K=200 components, dz=64, 3 spatial, n=6 neighbors.
// k_point: MFMA formulation. GEMM is (s x 68) @ (68 x 208pad):
//   A = [z(64) | s0,s1,s2 | 1], B = [mu^T | spmu^T | -0.5(|mu|^2+|spmu|^2)]
//   => acc = Lhat = z.mu + s.spmu - 0.5*norms. softmax(-U) == softmax(Lhat).
// Precision: hi/lo bf16 split, 3-term product (zh*mh + zl*mh + zh*ml); err ~1e-4.
#define KK 200
#define NT 13           // n-tiles of 16 (N padded to 208)
#define NNB 6

typedef __attribute__((ext_vector_type(8))) short short8;
typedef __attribute__((ext_vector_type(4))) float f32x4;
#define MFMA16 __builtin_amdgcn_mfma_f32_16x16x32_bf16

__device__ __forceinline__ unsigned short bfh(float f) {
    unsigned u = __float_as_uint(f);
    return (unsigned short)((u + 0x7fffu + ((u >> 16) & 1u)) >> 16);  // RNE
}
__device__ __forceinline__ float bf2f(unsigned short h) {
    return __uint_as_float(((unsigned)h) << 16);
}
__device__ __forceinline__ short8 z8() {
    short8 v;
#pragma unroll
    for (int j = 0; j < 8; ++j) v[j] = 0;
    return v;
}
__device__ __forceinline__ void cv2(float f, short8& hi, short8& lo, int j) {
    unsigned short h = bfh(f);
    hi[j] = (short)h;
    lo[j] = (short)bfh(f - bf2f(h));
}

// A-frag (16x16x32): lane holds A[m=lane&15][k=(lane>>4)*8 + j], j=0..7.
// B-frag:            lane holds B[k=(lane>>4)*8 + j][n=lane&15].
// C/D:               lane,reg -> D[row=(lane>>4)*4+reg][col=lane&15].
__global__ __launch_bounds__(512, 4) void
k_point(const float* __restrict__ Z, const float* __restrict__ S,
        const float* __restrict__ selmu, const float* __restrict__ spamu,
        unsigned short* __restrict__ Qc, float* __restrict__ pointbuf,
        int sRows, int mTiles)
{
    __shared__ short8 ldsBh[26 * 64];   // [t*2+s][lane] z-part hi frags  26624 B
    __shared__ short8 ldsBl[26 * 64];   //                z-part lo frags 26624 B
    __shared__ uint2  ldsB2h[NT * 16];  // [t][n&15] (sp0,sp1,sp2,norm) hi 1664 B
    __shared__ uint2  ldsB2l[NT * 16];  //                              lo 1664 B

    const int tid = threadIdx.x;

    // ---- stage B frags (z part): slot -> (t, kstep, lane) ----
    for (int slot = tid; slot < 26 * 64; slot += 512) {
        int L = slot & 63, ts = slot >> 6;       // ts = t*2 + s
        int t = ts >> 1, sstep = ts & 1;
        int n = t * 16 + (L & 15);
        int kb = sstep * 32 + (L >> 4) * 8;
        short8 hi = z8(), lo = z8();
        if (n < KK) {
            const float* mp = selmu + (size_t)n * 64 + kb;
            float4 a = *(const float4*)mp;
            float4 b = *(const float4*)(mp + 4);
            cv2(a.x, hi, lo, 0); cv2(a.y, hi, lo, 1); cv2(a.z, hi, lo, 2); cv2(a.w, hi, lo, 3);
            cv2(b.x, hi, lo, 4); cv2(b.y, hi, lo, 5); cv2(b.z, hi, lo, 6); cv2(b.w, hi, lo, 7);
        }
        ldsBh[slot] = hi;
        ldsBl[slot] = lo;
    }
    // ---- stage B2 frags (spatial + norm): k-step 2, only k_local 0..3 nonzero ----
    if (tid < NT * 16) {
        int n = tid;    // t = tid>>4, n&15 = tid&15 -> n == tid
        uint2 vh = make_uint2(0, 0), vl = make_uint2(0, 0);
        if (n < KK) {
            float p0 = spamu[n * 3 + 0], p1 = spamu[n * 3 + 1], p2 = spamu[n * 3 + 2];
            float nrm = p0 * p0 + p1 * p1 + p2 * p2;
            const float* mp = selmu + (size_t)n * 64;
#pragma unroll 8
            for (int k = 0; k < 64; ++k) { float m = mp[k]; nrm = fmaf(m, m, nrm); }
            nrm *= -0.5f;
            unsigned short h0 = bfh(p0), h1 = bfh(p1), h2 = bfh(p2), h3 = bfh(nrm);
            unsigned short g0 = bfh(p0 - bf2f(h0)), g1 = bfh(p1 - bf2f(h1));
            unsigned short g2 = bfh(p2 - bf2f(h2)), g3 = bfh(nrm - bf2f(h3));
            vh = make_uint2((unsigned)h0 | ((unsigned)h1 << 16), (unsigned)h2 | ((unsigned)h3 << 16));
            vl = make_uint2((unsigned)g0 | ((unsigned)g1 << 16), (unsigned)g2 | ((unsigned)g3 << 16));
        }
        ldsB2h[tid] = vh;
        ldsB2l[tid] = vl;
    }
    __syncthreads();   // only barrier; B frags read-only afterwards

    const int lane = tid & 63;
    const int q = lane >> 4;        // quad
    const int li = lane & 15;

    const float cLog = 0.5f * 67.0f * 1.8378770664093453f;

    for (int wg = blockIdx.x * 8 + (tid >> 6); wg < mTiles; wg += gridDim.x * 8) {
        const int m0 = wg * 16;
        const int rowA = (m0 + li < sRows) ? (m0 + li) : (sRows - 1);

        // ---- A frags: z hi/lo for 2 k-steps ----
        const float* zr = Z + (size_t)rowA * 64 + q * 8;
        float4 z0 = *(const float4*)zr;
        float4 z1 = *(const float4*)(zr + 4);
        float4 z2 = *(const float4*)(zr + 32);
        float4 z3 = *(const float4*)(zr + 36);
        short8 ah0 = z8(), al0 = z8(), ah1 = z8(), al1 = z8();
        cv2(z0.x, ah0, al0, 0); cv2(z0.y, ah0, al0, 1); cv2(z0.z, ah0, al0, 2); cv2(z0.w, ah0, al0, 3);
        cv2(z1.x, ah0, al0, 4); cv2(z1.y, ah0, al0, 5); cv2(z1.z, ah0, al0, 6); cv2(z1.w, ah0, al0, 7);
        cv2(z2.x, ah1, al1, 0); cv2(z2.y, ah1, al1, 1); cv2(z2.z, ah1, al1, 2); cv2(z2.w, ah1, al1, 3);
        cv2(z3.x, ah1, al1, 4); cv2(z3.y, ah1, al1, 5); cv2(z3.z, ah1, al1, 6); cv2(z3.w, ah1, al1, 7);

        // zz: each lane holds disjoint k-chunks of row m0+li; sum quads via xor16/32
        float zz = z0.x*z0.x + z0.y*z0.y + z0.z*z0.z + z0.w*z0.w
                 + z1.x*z1.x + z1.y*z1.y + z1.z*z1.z + z1.w*z1.w
                 + z2.x*z2.x + z2.y*z2.y + z2.z*z2.z + z2.w*z2.w
                 + z3.x*z3.x + z3.y*z3.y + z3.z*z3.z + z3.w*z3.w;
        zz += __shfl_xor(zz, 16);
        zz += __shfl_xor(zz, 32);

        // spatial row values (all lanes: row m0+li)
        float s0v = S[(size_t)rowA * 3 + 0];
        float s1v = S[(size_t)rowA * 3 + 1];
        float s2v = S[(size_t)rowA * 3 + 2];
        float cz = 0.5f * (zz + s0v * s0v + s1v * s1v + s2v * s2v) + cLog;

        // A2 frag (k-step 2): lanes 0..15 hold [s0,s1,s2,1,0,0,0,0] hi/lo
        short8 a2h = z8(), a2l = z8();
        if (lane < 16) {
            cv2(s0v, a2h, a2l, 0);
            cv2(s1v, a2h, a2l, 1);
            cv2(s2v, a2h, a2l, 2);
            a2h[3] = (short)bfh(1.0f);   // exact; lo stays 0
        }

        f32x4 acc[NT];
#pragma unroll
        for (int t = 0; t < NT; ++t) { f32x4 zv = {0.f, 0.f, 0.f, 0.f}; acc[t] = zv; }

#pragma unroll
        for (int t = 0; t < NT; ++t) {
            short8 b0 = ldsBh[(t * 2 + 0) * 64 + lane];
            short8 b1 = ldsBh[(t * 2 + 1) * 64 + lane];
            short8 c0 = ldsBl[(t * 2 + 0) * 64 + lane];
            short8 c1 = ldsBl[(t * 2 + 1) * 64 + lane];
            uint2 bh2 = make_uint2(0, 0), bl2 = make_uint2(0, 0);
            if (lane < 16) { bh2 = ldsB2h[t * 16 + lane]; bl2 = ldsB2l[t * 16 + lane]; }
            short8 B2h = z8(), B2l = z8();
            B2h[0] = (short)(bh2.x & 0xffff); B2h[1] = (short)(bh2.x >> 16);
            B2h[2] = (short)(bh2.y & 0xffff); B2h[3] = (short)(bh2.y >> 16);
            B2l[0] = (short)(bl2.x & 0xffff); B2l[1] = (short)(bl2.x >> 16);
            B2l[2] = (short)(bl2.y & 0xffff); B2l[3] = (short)(bl2.y >> 16);

            acc[t] = MFMA16(ah0, b0, acc[t], 0, 0, 0);
            acc[t] = MFMA16(ah1, b1, acc[t], 0, 0, 0);
            acc[t] = MFMA16(al0, b0, acc[t], 0, 0, 0);
            acc[t] = MFMA16(al1, b1, acc[t], 0, 0, 0);
            acc[t] = MFMA16(ah0, c0, acc[t], 0, 0, 0);
            acc[t] = MFMA16(ah1, c1, acc[t], 0, 0, 0);
            acc[t] = MFMA16(a2h, B2h, acc[t], 0, 0, 0);
            acc[t] = MFMA16(a2l, B2h, acc[t], 0, 0, 0);
            acc[t] = MFMA16(a2h, B2l, acc[t], 0, 0, 0);
        }

        // ---- epilogue: softmax per row; quad qq owns rows m0+4qq..+3 (reg r) ----
#pragma unroll
        for (int r = 0; r < 4; ++r) {
            const int row = m0 + q * 4 + r;
            float e[NT];
            float mx = -1e30f;
#pragma unroll
            for (int t = 0; t < NT; ++t) {
                float v = acc[t][r];
                if (t == 12 && li >= 8) v = -1e30f;   // n >= 200 pad
                e[t] = v;
                mx = fmaxf(mx, v);
            }
            mx = fmaxf(mx, __shfl_xor(mx, 1));
            mx = fmaxf(mx, __shfl_xor(mx, 2));
            mx = fmaxf(mx, __shfl_xor(mx, 4));
            mx = fmaxf(mx, __shfl_xor(mx, 8));
            float sl = 0.f, pl = 0.f;
#pragma unroll
            for (int t = 0; t < NT; ++t) {
                float v = e[t];
                float ee = __expf(v - mx);
                sl += ee;
                pl = fmaf(ee, v, pl);
                e[t] = ee;
            }
#pragma unroll
            for (int off = 1; off <= 8; off <<= 1) {
                sl += __shfl_xor(sl, off);
                pl += __shfl_xor(pl, off);
            }
            float inv = 1.0f / sl;
            if (row < sRows) {
#pragma unroll
                for (int t = 0; t < NT; ++t) {
                    if (t < 12 || li < 8) {
                        float qv = fminf(fmaxf(e[t] * inv, 1e-6f), 1.0f - 1e-6f);
                        Qc[(size_t)row * KK + t * 16 + li] = bfh(qv);
                    }
                }
                float czr = __shfl(cz, q * 4 + r);   // lane (q*4+r) holds that row's cz
                if (li == 0) pointbuf[row] = czr - pl * inv;
            }
        }
    }
}

// k_doublet: 2 rows per wave (one per 32-lane half); 25 lanes x 16B per gather.
__global__ __launch_bounds__(256) void
k_doublet(const unsigned short* __restrict__ Qc, const float* __restrict__ pointbuf,
          const int* __restrict__ D, float* __restrict__ out, int sRows)
{
    const int lane = threadIdx.x & 63;
    const int wave = threadIdx.x >> 6;
    const int r0 = (blockIdx.x * 4 + wave) * 2;
    if (r0 >= sRows) return;
    const int half = lane >> 5;
    const int l = lane & 31;
    const int row = r0 + half;
    const bool rv = (row < sRows);
    const int rowc = rv ? row : r0;
    const bool act = (l < 25) && rv;
    const int lc = (l < 25) ? l : 0;

    // own row chunk: 8 bf16 per lane
    uint4 ow = *(const uint4*)(Qc + (size_t)rowc * KK + lc * 8);
    float o0 = bf2f((unsigned short)(ow.x & 0xffff)), o1 = bf2f((unsigned short)(ow.x >> 16));
    float o2 = bf2f((unsigned short)(ow.y & 0xffff)), o3 = bf2f((unsigned short)(ow.y >> 16));
    float o4 = bf2f((unsigned short)(ow.z & 0xffff)), o5 = bf2f((unsigned short)(ow.z >> 16));
    float o6 = bf2f((unsigned short)(ow.w & 0xffff)), o7 = bf2f((unsigned short)(ow.w >> 16));

    int dj[NNB];
#pragma unroll
    for (int j = 0; j < NNB; ++j) dj[j] = D[(size_t)rowc * NNB + j];

    uint4 nbv[NNB];
#pragma unroll
    for (int j = 0; j < NNB; ++j) {
        int dd = (dj[j] >= 0) ? dj[j] : rowc;
        nbv[j] = *(const uint4*)(Qc + (size_t)dd * KK + lc * 8);
    }

    float pj[NNB];
#pragma unroll
    for (int j = 0; j < NNB; ++j) {
        uint4 nb = nbv[j];
        float t;
        t  = o0 * bf2f((unsigned short)(nb.x & 0xffff));
        t  = fmaf(o1, bf2f((unsigned short)(nb.x >> 16)), t);
        t  = fmaf(o2, bf2f((unsigned short)(nb.y & 0xffff)), t);
        t  = fmaf(o3, bf2f((unsigned short)(nb.y >> 16)), t);
        t  = fmaf(o4, bf2f((unsigned short)(nb.z & 0xffff)), t);
        t  = fmaf(o5, bf2f((unsigned short)(nb.z >> 16)), t);
        t  = fmaf(o6, bf2f((unsigned short)(nb.w & 0xffff)), t);
        t  = fmaf(o7, bf2f((unsigned short)(nb.w >> 16)), t);
        pj[j] = act ? t : 0.f;
    }
    // reduce within each 32-lane half (xor < 32 stays in half)
#pragma unroll
    for (int off = 1; off <= 16; off <<= 1) {
#pragma unroll
        for (int j = 0; j < NNB; ++j) pj[j] += __shfl_xor(pj[j], off);
    }
    float dbl = 0.f;
#pragma unroll
    for (int j = 0; j < NNB; ++j)
        if (dj[j] >= 0) dbl -= __logf(pj[j]);

    if (l == 0 && rv) out[row] = pointbuf[row] + dbl;
}

extern "C" void kernel_launch(void* const* d_in, const int* in_sizes, int n_in,
                              void* d_out, int out_size, void* d_ws, size_t ws_size,
                              hipStream_t stream) {
    const float* Z     = (const float*)d_in[0];
    const float* S     = (const float*)d_in[1];
    const int*   D     = (const int*)d_in[2];
    const float* selmu = (const float*)d_in[3];
    const float* spamu = (const float*)d_in[4];
    float* out = (float*)d_out;
    const int s = out_size;                    // 60000

    unsigned short* Qc = (unsigned short*)d_ws;                  // s*200 bf16 = 24 MB
    float* pointbuf = (float*)((char*)d_ws + (size_t)s * KK * 2);

    const int mTiles = (s + 15) / 16;          // 3750
    k_point<<<512, 512, 0, stream>>>(Z, S, selmu, spamu, Qc, pointbuf, s, mTiles);

    const int grid2 = ((s + 1) / 2 + 3) / 4;   // 2 rows/wave, 4 waves/block
    k_doublet<<<grid2, 256, 0, stream>>>(Qc, pointbuf, D, out, s);
}

// Round 4
// 111.269 us; speedup vs baseline: 1.6089x; 1.0040x over previous
//
#include <hip/hip_runtime.h>
#include <hip/hip_fp16.h>
#include <math.h>

// SpatialSelectiveMRF: s=60000 rows, K=200 components, dz=64, 3 spatial, n=6 neighbors.
// k_point: MFMA (s x 68) @ (68 x 208pad), A=[z|s|1], B=[mu^T|spmu^T|-0.5norm].
// Qc stored TWICE: bf16 rows (own-side, 400B) + e5m2 rows scaled x1024 (gather-side,
// padded to 256B = exactly 4 cache lines -> ~1.7x fewer random L3 lines in k_doublet).
#define KK 200
#define NT 13
#define NNB 6
#define Q8STRIDE 256

typedef __attribute__((ext_vector_type(8))) short short8;
typedef __attribute__((ext_vector_type(4))) float f32x4;
#define MFMA16 __builtin_amdgcn_mfma_f32_16x16x32_bf16

__device__ __forceinline__ unsigned short bfh(float f) {
    unsigned u = __float_as_uint(f);
    return (unsigned short)((u + 0x7fffu + ((u >> 16) & 1u)) >> 16);  // RNE
}
__device__ __forceinline__ float bf2f(unsigned short h) {
    return __uint_as_float(((unsigned)h) << 16);
}
__device__ __forceinline__ short8 z8() {
    short8 v;
#pragma unroll
    for (int j = 0; j < 8; ++j) v[j] = 0;
    return v;
}
__device__ __forceinline__ void cv2(float f, short8& hi, short8& lo, int j) {
    unsigned short h = bfh(f);
    hi[j] = (short)h;
    lo[j] = (short)bfh(f - bf2f(h));
}
// f32 -> e5m2 RNE via fp16 (e5m2 = top byte of fp16, round bit 8)
__device__ __forceinline__ unsigned char f2e5(float f) {
    unsigned short hb = __half_as_ushort(__float2half(f));   // RNE
    return (unsigned char)((hb + 0x7fu + ((hb >> 8) & 1u)) >> 8);
}
// 4 e5m2 bytes of w -> f32 (bits<<8 are valid fp16 patterns)
__device__ __forceinline__ void dec8(unsigned w, float* f) {
    f[0] = __half2float(__ushort_as_half((unsigned short)((w << 8) & 0xff00u)));
    f[1] = __half2float(__ushort_as_half((unsigned short)(w & 0xff00u)));
    f[2] = __half2float(__ushort_as_half((unsigned short)((w >> 8) & 0xff00u)));
    f[3] = __half2float(__ushort_as_half((unsigned short)((w >> 16) & 0xff00u)));
}

// A-frag (16x16x32): lane holds A[m=lane&15][k=(lane>>4)*8 + j].
// B-frag:            lane holds B[k=(lane>>4)*8 + j][n=lane&15].
// C/D:               lane,reg -> D[row=(lane>>4)*4+reg][col=lane&15].
__global__ __launch_bounds__(512, 4) void
k_point(const float* __restrict__ Z, const float* __restrict__ S,
        const float* __restrict__ selmu, const float* __restrict__ spamu,
        unsigned short* __restrict__ Qcb, unsigned char* __restrict__ Qc8,
        float* __restrict__ pointbuf, int sRows, int mTiles)
{
    __shared__ short8 ldsBh[26 * 64];
    __shared__ short8 ldsBl[26 * 64];
    __shared__ uint2  ldsB2h[NT * 16];
    __shared__ uint2  ldsB2l[NT * 16];

    const int tid = threadIdx.x;

    for (int slot = tid; slot < 26 * 64; slot += 512) {
        int L = slot & 63, ts = slot >> 6;
        int t = ts >> 1, sstep = ts & 1;
        int n = t * 16 + (L & 15);
        int kb = sstep * 32 + (L >> 4) * 8;
        short8 hi = z8(), lo = z8();
        if (n < KK) {
            const float* mp = selmu + (size_t)n * 64 + kb;
            float4 a = *(const float4*)mp;
            float4 b = *(const float4*)(mp + 4);
            cv2(a.x, hi, lo, 0); cv2(a.y, hi, lo, 1); cv2(a.z, hi, lo, 2); cv2(a.w, hi, lo, 3);
            cv2(b.x, hi, lo, 4); cv2(b.y, hi, lo, 5); cv2(b.z, hi, lo, 6); cv2(b.w, hi, lo, 7);
        }
        ldsBh[slot] = hi;
        ldsBl[slot] = lo;
    }
    if (tid < NT * 16) {
        int n = tid;
        uint2 vh = make_uint2(0, 0), vl = make_uint2(0, 0);
        if (n < KK) {
            float p0 = spamu[n * 3 + 0], p1 = spamu[n * 3 + 1], p2 = spamu[n * 3 + 2];
            float nrm = p0 * p0 + p1 * p1 + p2 * p2;
            const float* mp = selmu + (size_t)n * 64;
#pragma unroll 8
            for (int k = 0; k < 64; ++k) { float m = mp[k]; nrm = fmaf(m, m, nrm); }
            nrm *= -0.5f;
            unsigned short h0 = bfh(p0), h1 = bfh(p1), h2 = bfh(p2), h3 = bfh(nrm);
            unsigned short g0 = bfh(p0 - bf2f(h0)), g1 = bfh(p1 - bf2f(h1));
            unsigned short g2 = bfh(p2 - bf2f(h2)), g3 = bfh(nrm - bf2f(h3));
            vh = make_uint2((unsigned)h0 | ((unsigned)h1 << 16), (unsigned)h2 | ((unsigned)h3 << 16));
            vl = make_uint2((unsigned)g0 | ((unsigned)g1 << 16), (unsigned)g2 | ((unsigned)g3 << 16));
        }
        ldsB2h[tid] = vh;
        ldsB2l[tid] = vl;
    }
    __syncthreads();

    const int lane = tid & 63;
    const int q = lane >> 4;
    const int li = lane & 15;

    const float cLog = 0.5f * 67.0f * 1.8378770664093453f;

    for (int wg = blockIdx.x * 8 + (tid >> 6); wg < mTiles; wg += gridDim.x * 8) {
        const int m0 = wg * 16;
        const int rowA = (m0 + li < sRows) ? (m0 + li) : (sRows - 1);

        const float* zr = Z + (size_t)rowA * 64 + q * 8;
        float4 z0 = *(const float4*)zr;
        float4 z1 = *(const float4*)(zr + 4);
        float4 z2 = *(const float4*)(zr + 32);
        float4 z3 = *(const float4*)(zr + 36);
        short8 ah0 = z8(), al0 = z8(), ah1 = z8(), al1 = z8();
        cv2(z0.x, ah0, al0, 0); cv2(z0.y, ah0, al0, 1); cv2(z0.z, ah0, al0, 2); cv2(z0.w, ah0, al0, 3);
        cv2(z1.x, ah0, al0, 4); cv2(z1.y, ah0, al0, 5); cv2(z1.z, ah0, al0, 6); cv2(z1.w, ah0, al0, 7);
        cv2(z2.x, ah1, al1, 0); cv2(z2.y, ah1, al1, 1); cv2(z2.z, ah1, al1, 2); cv2(z2.w, ah1, al1, 3);
        cv2(z3.x, ah1, al1, 4); cv2(z3.y, ah1, al1, 5); cv2(z3.z, ah1, al1, 6); cv2(z3.w, ah1, al1, 7);

        float zz = z0.x*z0.x + z0.y*z0.y + z0.z*z0.z + z0.w*z0.w
                 + z1.x*z1.x + z1.y*z1.y + z1.z*z1.z + z1.w*z1.w
                 + z2.x*z2.x + z2.y*z2.y + z2.z*z2.z + z2.w*z2.w
                 + z3.x*z3.x + z3.y*z3.y + z3.z*z3.z + z3.w*z3.w;
        zz += __shfl_xor(zz, 16);
        zz += __shfl_xor(zz, 32);

        float s0v = S[(size_t)rowA * 3 + 0];
        float s1v = S[(size_t)rowA * 3 + 1];
        float s2v = S[(size_t)rowA * 3 + 2];
        float cz = 0.5f * (zz + s0v * s0v + s1v * s1v + s2v * s2v) + cLog;

        short8 a2h = z8(), a2l = z8();
        if (lane < 16) {
            cv2(s0v, a2h, a2l, 0);
            cv2(s1v, a2h, a2l, 1);
            cv2(s2v, a2h, a2l, 2);
            a2h[3] = (short)bfh(1.0f);
        }

        f32x4 acc[NT];
#pragma unroll
        for (int t = 0; t < NT; ++t) { f32x4 zv = {0.f, 0.f, 0.f, 0.f}; acc[t] = zv; }

#pragma unroll
        for (int t = 0; t < NT; ++t) {
            short8 b0 = ldsBh[(t * 2 + 0) * 64 + lane];
            short8 b1 = ldsBh[(t * 2 + 1) * 64 + lane];
            short8 c0 = ldsBl[(t * 2 + 0) * 64 + lane];
            short8 c1 = ldsBl[(t * 2 + 1) * 64 + lane];
            uint2 bh2 = make_uint2(0, 0), bl2 = make_uint2(0, 0);
            if (lane < 16) { bh2 = ldsB2h[t * 16 + lane]; bl2 = ldsB2l[t * 16 + lane]; }
            short8 B2h = z8(), B2l = z8();
            B2h[0] = (short)(bh2.x & 0xffff); B2h[1] = (short)(bh2.x >> 16);
            B2h[2] = (short)(bh2.y & 0xffff); B2h[3] = (short)(bh2.y >> 16);
            B2l[0] = (short)(bl2.x & 0xffff); B2l[1] = (short)(bl2.x >> 16);
            B2l[2] = (short)(bl2.y & 0xffff); B2l[3] = (short)(bl2.y >> 16);

            acc[t] = MFMA16(ah0, b0, acc[t], 0, 0, 0);
            acc[t] = MFMA16(ah1, b1, acc[t], 0, 0, 0);
            acc[t] = MFMA16(al0, b0, acc[t], 0, 0, 0);
            acc[t] = MFMA16(al1, b1, acc[t], 0, 0, 0);
            acc[t] = MFMA16(ah0, c0, acc[t], 0, 0, 0);
            acc[t] = MFMA16(ah1, c1, acc[t], 0, 0, 0);
            acc[t] = MFMA16(a2h, B2h, acc[t], 0, 0, 0);
            acc[t] = MFMA16(a2l, B2h, acc[t], 0, 0, 0);
            acc[t] = MFMA16(a2h, B2l, acc[t], 0, 0, 0);
        }

#pragma unroll
        for (int r = 0; r < 4; ++r) {
            const int row = m0 + q * 4 + r;
            float e[NT];
            float mx = -1e30f;
#pragma unroll
            for (int t = 0; t < NT; ++t) {
                float v = acc[t][r];
                if (t == 12 && li >= 8) v = -1e30f;
                e[t] = v;
                mx = fmaxf(mx, v);
            }
            mx = fmaxf(mx, __shfl_xor(mx, 1));
            mx = fmaxf(mx, __shfl_xor(mx, 2));
            mx = fmaxf(mx, __shfl_xor(mx, 4));
            mx = fmaxf(mx, __shfl_xor(mx, 8));
            float sl = 0.f, pl = 0.f;
#pragma unroll
            for (int t = 0; t < NT; ++t) {
                float v = e[t];
                float ee = __expf(v - mx);
                sl += ee;
                pl = fmaf(ee, v, pl);
                e[t] = ee;
            }
#pragma unroll
            for (int off = 1; off <= 8; off <<= 1) {
                sl += __shfl_xor(sl, off);
                pl += __shfl_xor(pl, off);
            }
            float inv = 1.0f / sl;
            if (row < sRows) {
#pragma unroll
                for (int t = 0; t < NT; ++t) {
                    if (t < 12 || li < 8) {
                        float qv = fminf(fmaxf(e[t] * inv, 1e-6f), 1.0f - 1e-6f);
                        Qcb[(size_t)row * KK + t * 16 + li] = bfh(qv);
                        Qc8[(size_t)row * Q8STRIDE + t * 16 + li] = f2e5(qv * 1024.0f);
                    }
                }
                float czr = __shfl(cz, q * 4 + r);
                if (li == 0) pointbuf[row] = czr - pl * inv;
            }
        }
    }
}

// k_doublet: XCD-matched to k_point. Grid 1024 = 2 x 512; b=g&511 reads rows written
// by k_point block b (512 % 8 == 0 keeps blockIdx%8 XCD mapping). Wave w owns tile
// b*8+w; sub-block (g>>9) takes rows [sub*8, sub*8+8) of it: 4 iters x 2 rows.
// Own row: bf16 (local-L2 hit). Gathers: e5m2 x1024, 256B stride = 4 aligned lines.
__global__ __launch_bounds__(512) void
k_doublet(const unsigned short* __restrict__ Qcb, const unsigned char* __restrict__ Qc8,
          const float* __restrict__ pointbuf, const int* __restrict__ D,
          float* __restrict__ out, int sRows, int mTiles)
{
    const int wave = threadIdx.x >> 6;
    const int lane = threadIdx.x & 63;
    const int half = lane >> 5;
    const int l = lane & 31;
    const int sub = blockIdx.x >> 9;
    const int b = blockIdx.x & 511;
    const int T = b * 8 + wave;
    if (T >= mTiles) return;
    const int rbase = T * 16 + sub * 8;

    const bool act = (l < 25);
    const int lc = act ? l : 0;
    const float LN1024 = 6.93147180559945f;

    int   row  = rbase + half;
    int   rowc = (row < sRows) ? row : (sRows - 1);
    uint4 own  = *(const uint4*)(Qcb + (size_t)rowc * KK + lc * 8);
    int   dj[NNB];
    uint2 nb[NNB];
#pragma unroll
    for (int j = 0; j < NNB; ++j) dj[j] = D[(size_t)rowc * NNB + j];
#pragma unroll
    for (int j = 0; j < NNB; ++j) {
        int dd = (dj[j] >= 0) ? dj[j] : rowc;
        nb[j] = *(const uint2*)(Qc8 + (size_t)dd * Q8STRIDE + lc * 8);
    }

    for (int it = 0; it < 4; ++it) {
        // ---- prefetch next iteration before consuming current ----
        int   rowN = 0, rowcN = 0;
        uint4 ownN = make_uint4(0, 0, 0, 0);
        int   djN[NNB];
        uint2 nbN[NNB];
        if (it < 3) {
            rowN  = rbase + (it + 1) * 2 + half;
            rowcN = (rowN < sRows) ? rowN : (sRows - 1);
            ownN  = *(const uint4*)(Qcb + (size_t)rowcN * KK + lc * 8);
#pragma unroll
            for (int j = 0; j < NNB; ++j) djN[j] = D[(size_t)rowcN * NNB + j];
#pragma unroll
            for (int j = 0; j < NNB; ++j) {
                int dd = (djN[j] >= 0) ? djN[j] : rowcN;
                nbN[j] = *(const uint2*)(Qc8 + (size_t)dd * Q8STRIDE + lc * 8);
            }
        }

        // ---- consume current ----
        float o[8];
        o[0] = bf2f((unsigned short)(own.x & 0xffff)); o[1] = bf2f((unsigned short)(own.x >> 16));
        o[2] = bf2f((unsigned short)(own.y & 0xffff)); o[3] = bf2f((unsigned short)(own.y >> 16));
        o[4] = bf2f((unsigned short)(own.z & 0xffff)); o[5] = bf2f((unsigned short)(own.z >> 16));
        o[6] = bf2f((unsigned short)(own.w & 0xffff)); o[7] = bf2f((unsigned short)(own.w >> 16));

        float pj[NNB];
#pragma unroll
        for (int j = 0; j < NNB; ++j) {
            float bv[8];
            dec8(nb[j].x, bv);
            dec8(nb[j].y, bv + 4);
            float t = o[0] * bv[0];
            t = fmaf(o[1], bv[1], t); t = fmaf(o[2], bv[2], t); t = fmaf(o[3], bv[3], t);
            t = fmaf(o[4], bv[4], t); t = fmaf(o[5], bv[5], t); t = fmaf(o[6], bv[6], t);
            t = fmaf(o[7], bv[7], t);
            pj[j] = act ? t : 0.f;
        }
#pragma unroll
        for (int off = 1; off <= 16; off <<= 1) {
#pragma unroll
            for (int j = 0; j < NNB; ++j) pj[j] += __shfl_xor(pj[j], off);
        }
        float dbl = 0.f;
#pragma unroll
        for (int j = 0; j < NNB; ++j)
            if (dj[j] >= 0) dbl += LN1024 - __logf(pj[j]);   // co = pj / 1024

        if (l == 0 && row < sRows) out[row] = pointbuf[row] + dbl;

        // ---- rotate pipeline ----
        row = rowN; rowc = rowcN; own = ownN;
#pragma unroll
        for (int j = 0; j < NNB; ++j) { dj[j] = djN[j]; nb[j] = nbN[j]; }
    }
}

extern "C" void kernel_launch(void* const* d_in, const int* in_sizes, int n_in,
                              void* d_out, int out_size, void* d_ws, size_t ws_size,
                              hipStream_t stream) {
    const float* Z     = (const float*)d_in[0];
    const float* S     = (const float*)d_in[1];
    const int*   D     = (const int*)d_in[2];
    const float* selmu = (const float*)d_in[3];
    const float* spamu = (const float*)d_in[4];
    float* out = (float*)d_out;
    const int s = out_size;                    // 60000

    const size_t qcbB = (size_t)s * KK * 2;    // 24,000,000 B (bf16 rows)
    const size_t qc8B = (size_t)s * Q8STRIDE;  // 15,360,000 B (e5m2 rows, padded)
    unsigned short* Qcb = (unsigned short*)d_ws;
    unsigned char*  Qc8 = (unsigned char*)d_ws + qcbB;
    float* pointbuf = (float*)((char*)d_ws + qcbB + qc8B);

    const int mTiles = (s + 15) / 16;          // 3750
    const int grid1 = (mTiles + 7) / 8;        // 469: wave w of block b -> tile b*8+w
    k_point<<<grid1, 512, 0, stream>>>(Z, S, selmu, spamu, Qcb, Qc8, pointbuf, s, mTiles);

    k_doublet<<<1024, 512, 0, stream>>>(Qcb, Qc8, pointbuf, D, out, s, mTiles);
}